// Round 4
// baseline (946.237 us; speedup 1.0000x reference)
//
#include <hip/hip_runtime.h>
#include <math.h>

#define BATCH_N   8192
#define IN_SIZE_N  512
#define HIDDEN_N  2048
#define HEADS_N     64
#define RANK_N      16
#define PN        1152   // padded FM-head GEMM width: 64 lin + 1024 vx + 64 pad

typedef short s16x4 __attribute__((ext_vector_type(4)));
typedef short s16x8 __attribute__((ext_vector_type(8)));
typedef float f32x4 __attribute__((ext_vector_type(4)));
typedef unsigned int u32;

__device__ __forceinline__ short f2bf(float f) {
    __bf16 b = (__bf16)f; short r; __builtin_memcpy(&r, &b, 2); return r;
}
__device__ __forceinline__ float bf2f(short s) {
    __bf16 b; __builtin_memcpy(&b, &s, 2); return (float)b;
}
__device__ __forceinline__ void gld16(const void* g, void* l) {
    __builtin_amdgcn_global_load_lds(
        (const __attribute__((address_space(1))) u32*)g,
        (__attribute__((address_space(3))) u32*)l, 16, 0, 0);
}

// ---------------------------------------------------------------------------
// Split-bf16 MFMA GEMM, counted-vmcnt triple-buffered pipeline.
// C = act(A @ Bt^T + bias); A=[M][K] hi/lo bf16, Bt=[N][K] hi/lo bf16.
// Tile BM x 128, BK=32, 512 threads (8 waves, 4M x 2N -> 64x64 per wave).
// LDS swizzle (bank-conflict-free, verified by quarter-wave bank math):
//   16B chunk (row, j) at LDS index row*4 + j holds k-segment ks = j ^ ((row>>2)&3).
//   Read frag (row,ks) at el = row*32 + ((ks ^ ((row>>2)&3))<<3)
//   -> per 16-lane quarter, bank-group = (u + 4v) % 8 (l15=4u+v): exact 2-way.
//   Staged via pre-swizzled GLOBAL source (LDS dest linear; G21-compliant).
// ---------------------------------------------------------------------------
template<int BM, bool ACT>
__global__ __launch_bounds__(512)
void gemm8(const short* __restrict__ Ahi, const short* __restrict__ Alo,
           const short* __restrict__ Bhi, const short* __restrict__ Blo,
           const float* __restrict__ bias,
           short* __restrict__ Chi, short* __restrict__ Clo,
           float* __restrict__ Cf,
           int GX, int N, int K)
{
    constexpr int BN = 128;
    constexpr int MF = BM / 64;              // M-frags per wave (4 or 2) = phases
    constexpr int NG = (BM == 256) ? 6 : 4;  // gld issues per K-tile
    constexpr int AH = 0;
    constexpr int AL = BM * 32;
    constexpr int BH = 2 * BM * 32;
    constexpr int BL = 2 * BM * 32 + BN * 32;
    constexpr int SBUF = 2 * BM * 32 + 2 * BN * 32;
    __shared__ __align__(16) short lds[3 * SBUF];

    const int tid = threadIdx.x;
    const int lane = tid & 63, wave = tid >> 6;
    const int wr = wave >> 1, wc = wave & 1;          // 4M x 2N
    const int l15 = lane & 15, ks = lane >> 4;

    // XCD-aware swizzle (gridDim.x % 8 == 0 for all our launches)
    const int flat = blockIdx.x;
    const int wg = (flat & 7) * (gridDim.x >> 3) + (flat >> 3);
    const int bn = wg % GX, bm = wg / GX;

    const short* Ab_h = Ahi + (size_t)bm * BM * K;
    const short* Ab_l = Alo + (size_t)bm * BM * K;
    const short* Bb_h = Bhi + (size_t)bn * BN * K;
    const short* Bb_l = Blo + (size_t)bn * BN * K;

    // staging: LDS chunk c (linear, c = tid [+512]) <- global (row=c>>2,
    // seg = (c&3) ^ ((c>>4)&3)). LDS dest wave-uniform base + lane*16B.
    const int rA0 = tid >> 2;
    const int kA0 = (tid & 3) ^ ((tid >> 4) & 3);
    const size_t sA0 = (size_t)rA0 * K + kA0 * 8;
    const size_t sA1 = sA0 + (size_t)128 * K;     // chunk tid+512 (BM=256 only)
    const size_t sB  = sA0;
    const int d0 = (tid & ~63) * 8;               // wave-uniform LDS el offset
    const int d1 = d0 + 512 * 8;

    // frag reads: el = row*32 + ksx; (row>>2)&3 == (l15>>2)&3 for 16-aligned bases
    const int ksx = (ks ^ ((l15 >> 2) & 3)) << 3;
    int aoff[MF], boff[4];
#pragma unroll
    for (int m = 0; m < MF; ++m)
        aoff[m] = (wr * (BM / 4) + m * 16 + l15) * 32 + ksx;
#pragma unroll
    for (int n = 0; n < 4; ++n)
        boff[n] = (wc * 64 + n * 16 + l15) * 32 + ksx;

    f32x4 acc[MF][4] = {};
    const int NT = K >> 5;

    auto issue = [&](int g, short* nb, int k2) {
        if constexpr (BM == 256) {
            switch (g) {
            case 0: gld16(Ab_h + sA0 + k2, &nb[AH + d0]); break;
            case 1: gld16(Ab_h + sA1 + k2, &nb[AH + d1]); break;
            case 2: gld16(Ab_l + sA0 + k2, &nb[AL + d0]); break;
            case 3: gld16(Ab_l + sA1 + k2, &nb[AL + d1]); break;
            case 4: gld16(Bb_h + sB  + k2, &nb[BH + d0]); break;
            case 5: gld16(Bb_l + sB  + k2, &nb[BL + d0]); break;
            }
        } else {
            switch (g) {
            case 0: gld16(Ab_h + sA0 + k2, &nb[AH + d0]); break;
            case 1: gld16(Ab_l + sA0 + k2, &nb[AL + d0]); break;
            case 2: gld16(Bb_h + sB  + k2, &nb[BH + d0]); break;
            case 3: gld16(Bb_l + sB  + k2, &nb[BL + d0]); break;
            }
        }
    };

    // prologue: stage tiles 0 and 1; wait own tile-0 glds (leave tile 1 in flight)
#pragma unroll
    for (int g = 0; g < NG; ++g) issue(g, &lds[0], 0);
#pragma unroll
    for (int g = 0; g < NG; ++g) issue(g, &lds[SBUF], 32);
    if constexpr (BM == 256) asm volatile("s_waitcnt vmcnt(6)" ::: "memory");
    else                     asm volatile("s_waitcnt vmcnt(4)" ::: "memory");
    __builtin_amdgcn_s_barrier();

    int slot = 0, islot = 2;
#pragma unroll 1
    for (int t = 0; t < NT; ++t) {
        short* buf = &lds[slot * SBUF];
        short* nb  = &lds[islot * SBUF];
        const bool valid = (t + 2 < NT);
        const int k2 = (t + 2) << 5;
        s16x8 bh[4], bl[4];
#pragma unroll
        for (int p = 0; p < MF; ++p) {
            if (p == 0) {
#pragma unroll
                for (int n = 0; n < 4; ++n) {
                    bh[n] = *(const s16x8*)&buf[BH + boff[n]];
                    bl[n] = *(const s16x8*)&buf[BL + boff[n]];
                }
            }
            const s16x8 ah = *(const s16x8*)&buf[AH + aoff[p]];
            const s16x8 al = *(const s16x8*)&buf[AL + aoff[p]];
            if (valid) {
                if (2 * p < NG)     issue(2 * p,     nb, k2);
                if (2 * p + 1 < NG) issue(2 * p + 1, nb, k2);
            }
            __builtin_amdgcn_s_barrier();
            asm volatile("s_waitcnt lgkmcnt(0)" ::: "memory");
            __builtin_amdgcn_sched_barrier(0);
            __builtin_amdgcn_s_setprio(1);
#pragma unroll
            for (int n = 0; n < 4; ++n) {
                acc[p][n] = __builtin_amdgcn_mfma_f32_16x16x32_bf16(ah, bh[n], acc[p][n], 0, 0, 0);
                acc[p][n] = __builtin_amdgcn_mfma_f32_16x16x32_bf16(ah, bl[n], acc[p][n], 0, 0, 0);
                acc[p][n] = __builtin_amdgcn_mfma_f32_16x16x32_bf16(al, bh[n], acc[p][n], 0, 0, 0);
            }
            __builtin_amdgcn_s_setprio(0);
            __builtin_amdgcn_sched_barrier(0);
            if (p == MF - 1) {
                if (valid) {
                    if constexpr (BM == 256) asm volatile("s_waitcnt vmcnt(6)" ::: "memory");
                    else                     asm volatile("s_waitcnt vmcnt(4)" ::: "memory");
                } else {
                    asm volatile("s_waitcnt vmcnt(0)" ::: "memory");
                }
            }
            __builtin_amdgcn_s_barrier();
        }
        slot  = (slot  == 2) ? 0 : slot + 1;
        islot = (islot == 2) ? 0 : islot + 1;
    }

    // epilogue (C/D map: col = lane&15, row = (lane>>4)*4 + j)
    const int row0 = bm * BM + wr * (BM / 4);
    const int col0 = bn * BN + wc * 64;
#pragma unroll
    for (int n = 0; n < 4; ++n) {
        const int col = col0 + n * 16 + l15;
        float bv = 0.0f;
        if constexpr (ACT) bv = bias[col];
#pragma unroll
        for (int m = 0; m < MF; ++m) {
#pragma unroll
            for (int j = 0; j < 4; ++j) {
                const int row = row0 + m * 16 + ks * 4 + j;
                float v = acc[m][n][j];
                if constexpr (ACT) {
                    v = tanhf(v + bv);
                    const short h = f2bf(v);
                    Chi[(size_t)row * N + col] = h;
                    Clo[(size_t)row * N + col] = f2bf(v - bf2f(h));
                } else {
                    Cf[(size_t)row * N + col] = v;
                }
            }
        }
    }
}

// f32 src -> hi/lo bf16 split (grid-stride, float4). Elements >= n_src -> 0.
__global__ __launch_bounds__(256)
void pack_split(const float* __restrict__ src, long n_src,
                short* __restrict__ hi, short* __restrict__ lo, long n_total)
{
    const long stride = (long)gridDim.x * 1024;
    for (long i4 = ((long)blockIdx.x * 256 + threadIdx.x) * 4; i4 < n_total; i4 += stride) {
        float a[4] = {0.f, 0.f, 0.f, 0.f};
        if (i4 < n_src) {
            const float4 v = *(const float4*)&src[i4];
            a[0] = v.x; a[1] = v.y; a[2] = v.z; a[3] = v.w;
        }
        s16x4 h, l;
#pragma unroll
        for (int j = 0; j < 4; ++j) {
            h[j] = f2bf(a[j]);
            l[j] = f2bf(a[j] - bf2f(h[j]));
        }
        *(s16x4*)&hi[i4] = h;
        *(s16x4*)&lo[i4] = l;
    }
}

// W[K][N] f32 -> Thi/Tlo[N][K] bf16. Block (32,8), 32x32 LDS tile.
__global__ __launch_bounds__(256)
void transpose_split(const float* __restrict__ W,
                     short* __restrict__ Thi, short* __restrict__ Tlo,
                     int K, int N)
{
    __shared__ float t[32][33];
    const int tx = threadIdx.x, ty = threadIdx.y;
    const int n0 = blockIdx.x * 32, k0 = blockIdx.y * 32;
#pragma unroll
    for (int i = 0; i < 4; ++i)
        t[ty * 4 + i][tx] = W[(size_t)(k0 + ty * 4 + i) * N + n0 + tx];
    __syncthreads();
#pragma unroll
    for (int i = 0; i < 4; ++i) {
        const int n = n0 + ty * 4 + i;
        const float v = t[tx][ty * 4 + i];
        const short h = f2bf(v);
        Thi[(size_t)n * K + k0 + tx] = h;
        Tlo[(size_t)n * K + k0 + tx] = f2bf(v - bf2f(h));
    }
}

// Vsq[h][d] = sum_r V[h][r][d]^2
__global__ __launch_bounds__(256)
void fm_vsq(const float* __restrict__ V, float* __restrict__ Vsq)
{
    const int h = blockIdx.x;
    for (int d = threadIdx.x; d < HIDDEN_N; d += 256) {
        float s = 0.0f;
#pragma unroll
        for (int r = 0; r < RANK_N; ++r) {
            const float v = V[((size_t)h * RANK_N + r) * HIDDEN_N + d];
            s = fmaf(v, v, s);
        }
        Vsq[(size_t)h * HIDDEN_N + d] = s;
    }
}

// D[m][64] = (h3[m].^2) @ Vsq^T ; A from hi/lo bf16, 32x64 tile, BK=16
__global__ __launch_bounds__(256)
void gemm_diag(const short* __restrict__ Ahi, const short* __restrict__ Alo,
               const float* __restrict__ Vsq, float* __restrict__ D, int K)
{
    __shared__ float As[16][36];
    __shared__ float Bs[16][68];
    const int tid = threadIdx.x;
    const int tr = tid >> 4, tc = tid & 15;
    const int bm = blockIdx.x;
    float acc[2][4] = {};
    for (int k0 = 0; k0 < K; k0 += 16) {
        if (tid < 128) {
            const int row = tid >> 2, cv = (tid & 3) * 4;
            const size_t off = (size_t)(bm * 32 + row) * K + k0 + cv;
            const s16x4 h = *(const s16x4*)&Ahi[off];
            const s16x4 l = *(const s16x4*)&Alo[off];
#pragma unroll
            for (int j = 0; j < 4; ++j) {
                const float f = bf2f(h[j]) + bf2f(l[j]);
                As[cv + j][row] = f * f;
            }
        }
        {
            const int row = tid >> 2, cv = (tid & 3) * 4;
            const float4 v = *(const float4*)&Vsq[(size_t)row * K + k0 + cv];
            Bs[cv + 0][row] = v.x; Bs[cv + 1][row] = v.y;
            Bs[cv + 2][row] = v.z; Bs[cv + 3][row] = v.w;
        }
        __syncthreads();
#pragma unroll
        for (int kk = 0; kk < 16; ++kk) {
            const float a0 = As[kk][tr * 2], a1 = As[kk][tr * 2 + 1];
            const float4 b = *(const float4*)&Bs[kk][tc * 4];
            acc[0][0] = fmaf(a0, b.x, acc[0][0]); acc[0][1] = fmaf(a0, b.y, acc[0][1]);
            acc[0][2] = fmaf(a0, b.z, acc[0][2]); acc[0][3] = fmaf(a0, b.w, acc[0][3]);
            acc[1][0] = fmaf(a1, b.x, acc[1][0]); acc[1][1] = fmaf(a1, b.y, acc[1][1]);
            acc[1][2] = fmaf(a1, b.z, acc[1][2]); acc[1][3] = fmaf(a1, b.w, acc[1][3]);
        }
        __syncthreads();
    }
#pragma unroll
    for (int i = 0; i < 2; ++i)
#pragma unroll
        for (int j = 0; j < 4; ++j)
            D[(size_t)(bm * 32 + tr * 2 + i) * 64 + tc * 4 + j] = acc[i][j];
}

// out[h, boff+b] = w0[h] + P[b,h] + 0.5*(sum_r P[b,64+16h+r]^2 - D[b,h])
// one wave per batch row; fully coalesced P reads.
__global__ __launch_bounds__(256)
void fm_combine(const float* __restrict__ P, const float* __restrict__ D,
                const float* __restrict__ w0, float* __restrict__ out, int boff)
{
    const int wave = threadIdx.x >> 6, lane = threadIdx.x & 63;
    const int b = blockIdx.x * 4 + wave;
    const float* Pb = P + (size_t)b * PN;
    const float* Db = D + (size_t)b * 64;
    const int hl = lane & 15, part = lane >> 4;
#pragma unroll
    for (int hb = 0; hb < 4; ++hb) {
        const float4 v = *(const float4*)&Pb[64 + hb * 256 + hl * 16 + part * 4];
        float q = fmaf(v.x, v.x, fmaf(v.y, v.y, fmaf(v.z, v.z, v.w * v.w)));
        q += __shfl_xor(q, 16);
        q += __shfl_xor(q, 32);
        if (part == 0) {
            const int h = hb * 16 + hl;
            out[(size_t)h * BATCH_N + boff + b] = w0[h] + Pb[h] + 0.5f * (q - Db[h]);
        }
    }
}

extern "C" void kernel_launch(void* const* d_in, const int* in_sizes, int n_in,
                              void* d_out, int out_size, void* d_ws, size_t ws_size,
                              hipStream_t stream)
{
    const float* x   = (const float*)d_in[0];
    const float* W1  = (const float*)d_in[1];
    const float* b1  = (const float*)d_in[2];
    const float* W2  = (const float*)d_in[3];
    const float* b2  = (const float*)d_in[4];
    const float* W3  = (const float*)d_in[5];
    const float* b3  = (const float*)d_in[6];
    const float* fw0 = (const float*)d_in[7];
    const float* fw  = (const float*)d_in[8];
    const float* fV  = (const float*)d_in[9];
    float* out = (float*)d_out;

    const int CH = 4096;   // 2 chunks: keeps grid = 256 blocks and ws <= ~112 MB

    char* ws = (char*)d_ws;
    size_t o = 0;
    auto alloc = [&](size_t bytes) { void* p = ws + o; o += (bytes + 255) & ~(size_t)255; return p; };

    short* W1h = (short*)alloc((size_t)HIDDEN_N * IN_SIZE_N * 2);
    short* W1l = (short*)alloc((size_t)HIDDEN_N * IN_SIZE_N * 2);
    short* W2h = (short*)alloc((size_t)HIDDEN_N * HIDDEN_N * 2);
    short* W2l = (short*)alloc((size_t)HIDDEN_N * HIDDEN_N * 2);
    short* W3h = (short*)alloc((size_t)HIDDEN_N * HIDDEN_N * 2);
    short* W3l = (short*)alloc((size_t)HIDDEN_N * HIDDEN_N * 2);
    short* PBh = (short*)alloc((size_t)PN * HIDDEN_N * 2);
    short* PBl = (short*)alloc((size_t)PN * HIDDEN_N * 2);
    float* Vsq = (float*)alloc((size_t)HEADS_N * HIDDEN_N * 4);
    short* hAh = (short*)alloc((size_t)CH * HIDDEN_N * 2);
    short* hAl = (short*)alloc((size_t)CH * HIDDEN_N * 2);
    char*  hBb = (char*) alloc((size_t)CH * HIDDEN_N * 4);   // hBh+hBl contiguous
    short* hBh = (short*)hBb;
    short* hBl = hBh + (size_t)CH * HIDDEN_N;
    short* xh  = (short*)hBb;                      // alias (dead when h2/P live)
    short* xl  = xh + (size_t)CH * IN_SIZE_N;
    float* P   = (float*)hBb;                      // [CH][PN] f32, alias of hB
    float* Dg  = (float*)(hBb + (size_t)CH * PN * 4);

    const dim3 blk(256, 1, 1);
    const dim3 blk512(512, 1, 1);

    // one-time packs
    transpose_split<<<dim3(HIDDEN_N / 32, IN_SIZE_N / 32), dim3(32, 8), 0, stream>>>(W1, W1h, W1l, IN_SIZE_N, HIDDEN_N);
    transpose_split<<<dim3(HIDDEN_N / 32, HIDDEN_N / 32), dim3(32, 8), 0, stream>>>(W2, W2h, W2l, HIDDEN_N, HIDDEN_N);
    transpose_split<<<dim3(HIDDEN_N / 32, HIDDEN_N / 32), dim3(32, 8), 0, stream>>>(W3, W3h, W3l, HIDDEN_N, HIDDEN_N);
    pack_split<<<dim3(128), blk, 0, stream>>>(fw, (long)HEADS_N * HIDDEN_N, PBh, PBl, (long)HEADS_N * HIDDEN_N);
    pack_split<<<dim3(1024), blk, 0, stream>>>(fV, (long)HEADS_N * RANK_N * HIDDEN_N,
                                               PBh + (size_t)HEADS_N * HIDDEN_N,
                                               PBl + (size_t)HEADS_N * HIDDEN_N,
                                               (long)(PN - HEADS_N) * HIDDEN_N);
    fm_vsq<<<dim3(HEADS_N), blk, 0, stream>>>(fV, Vsq);

    for (int c = 0; c < 2; ++c) {
        pack_split<<<dim3(1024), blk, 0, stream>>>(x + (size_t)c * CH * IN_SIZE_N,
                                                   (long)CH * IN_SIZE_N, xh, xl, (long)CH * IN_SIZE_N);
        // h1 = tanh(x W1 + b1)
        gemm8<256, true><<<dim3((HIDDEN_N / 128) * (CH / 256)), blk512, 0, stream>>>(
            xh, xl, W1h, W1l, b1, hAh, hAl, nullptr, HIDDEN_N / 128, HIDDEN_N, IN_SIZE_N);
        // h2
        gemm8<256, true><<<dim3((HIDDEN_N / 128) * (CH / 256)), blk512, 0, stream>>>(
            hAh, hAl, W2h, W2l, b2, hBh, hBl, nullptr, HIDDEN_N / 128, HIDDEN_N, HIDDEN_N);
        // h3 (overwrites h1)
        gemm8<256, true><<<dim3((HIDDEN_N / 128) * (CH / 256)), blk512, 0, stream>>>(
            hBh, hBl, W3h, W3l, b3, hAh, hAl, nullptr, HIDDEN_N / 128, HIDDEN_N, HIDDEN_N);
        // P = h3 @ [fm_w; fm_V]^T   (f32 out, overwrites h2 region)
        gemm8<128, false><<<dim3((PN / 128) * (CH / 128)), blk512, 0, stream>>>(
            hAh, hAl, PBh, PBl, nullptr, nullptr, nullptr, P, PN / 128, PN, HIDDEN_N);
        // D = h3^2 @ Vsq^T
        gemm_diag<<<dim3(CH / 32), blk, 0, stream>>>(hAh, hAl, Vsq, Dg, HIDDEN_N);
        fm_combine<<<dim3(CH / 4), blk, 0, stream>>>(P, Dg, fw0, out, c * CH);
    }
}

// Round 5
// 767.361 us; speedup vs baseline: 1.2331x; 1.2331x over previous
//
#include <hip/hip_runtime.h>
#include <math.h>

#define BATCH_N   8192
#define IN_SIZE_N  512
#define HIDDEN_N  2048
#define HEADS_N     64
#define RANK_N      16
#define PN        1152   // padded FM-head GEMM width: 64 lin + 1024 vx + 64 pad

typedef short s16x4 __attribute__((ext_vector_type(4)));
typedef short s16x8 __attribute__((ext_vector_type(8)));
typedef float f32x4 __attribute__((ext_vector_type(4)));
typedef unsigned int u32;

__device__ __forceinline__ short f2bf(float f) {
    __bf16 b = (__bf16)f; short r; __builtin_memcpy(&r, &b, 2); return r;
}
__device__ __forceinline__ float bf2f(short s) {
    __bf16 b; __builtin_memcpy(&b, &s, 2); return (float)b;
}
__device__ __forceinline__ void gld16(const void* g, void* l) {
    __builtin_amdgcn_global_load_lds(
        (const __attribute__((address_space(1))) u32*)g,
        (__attribute__((address_space(3))) u32*)l, 16, 0, 0);
}

// ---------------------------------------------------------------------------
// Split-bf16 MFMA GEMM, counted-vmcnt triple-buffered pipeline.
// C = act(A @ Bt^T + bias); A=[M][K] hi/lo bf16, Bt=[N][K] hi/lo bf16.
// Tile BM x 128, BK=32, 512 threads (8 waves, 4M x 2N -> 64x64 per wave).
// ONE raw s_barrier + one counted vmcnt per K-tile (R5 change): intra-tile
// phase barriers removed — triple buffering makes them unnecessary for
// correctness, and R4 showed they cost ~55% of the kernel (8 barriers +
// 4 lgkmcnt(0) drains per tile -> MfmaUtil pinned at 36%). ds_reads are
// plain C++ loads; the compiler emits counted lgkmcnt per use (m97 asm).
// ---------------------------------------------------------------------------
template<int BM, bool ACT>
__global__ __launch_bounds__(512)
void gemm8(const short* __restrict__ Ahi, const short* __restrict__ Alo,
           const short* __restrict__ Bhi, const short* __restrict__ Blo,
           const float* __restrict__ bias,
           short* __restrict__ Chi, short* __restrict__ Clo,
           float* __restrict__ Cf,
           int GX, int N, int K)
{
    constexpr int BN = 128;
    constexpr int MF = BM / 64;              // M-frags per wave (4 or 2) = phases
    constexpr int NG = (BM == 256) ? 6 : 4;  // gld issues per K-tile
    constexpr int AH = 0;
    constexpr int AL = BM * 32;
    constexpr int BH = 2 * BM * 32;
    constexpr int BL = 2 * BM * 32 + BN * 32;
    constexpr int SBUF = 2 * BM * 32 + 2 * BN * 32;
    __shared__ __align__(16) short lds[3 * SBUF];

    const int tid = threadIdx.x;
    const int lane = tid & 63, wave = tid >> 6;
    const int wr = wave >> 1, wc = wave & 1;          // 4M x 2N
    const int l15 = lane & 15, ks = lane >> 4;

    // XCD-aware swizzle (gridDim.x % 8 == 0 for all our launches)
    const int flat = blockIdx.x;
    const int wg = (flat & 7) * (gridDim.x >> 3) + (flat >> 3);
    const int bn = wg % GX, bm = wg / GX;

    const short* Ab_h = Ahi + (size_t)bm * BM * K;
    const short* Ab_l = Alo + (size_t)bm * BM * K;
    const short* Bb_h = Bhi + (size_t)bn * BN * K;
    const short* Bb_l = Blo + (size_t)bn * BN * K;

    // staging: LDS chunk c (linear, c = tid [+512]) <- global (row=c>>2,
    // seg = (c&3) ^ ((c>>4)&3)). LDS dest wave-uniform base + lane*16B.
    const int rA0 = tid >> 2;
    const int kA0 = (tid & 3) ^ ((tid >> 4) & 3);
    const size_t sA0 = (size_t)rA0 * K + kA0 * 8;
    const size_t sA1 = sA0 + (size_t)128 * K;     // chunk tid+512 (BM=256 only)
    const size_t sB  = sA0;
    const int d0 = (tid & ~63) * 8;               // wave-uniform LDS el offset
    const int d1 = d0 + 512 * 8;

    // frag reads: el = row*32 + ksx; (row>>2)&3 == (l15>>2)&3 for 16-aligned bases
    const int ksx = (ks ^ ((l15 >> 2) & 3)) << 3;
    int aoff[MF], boff[4];
#pragma unroll
    for (int m = 0; m < MF; ++m)
        aoff[m] = (wr * (BM / 4) + m * 16 + l15) * 32 + ksx;
#pragma unroll
    for (int n = 0; n < 4; ++n)
        boff[n] = (wc * 64 + n * 16 + l15) * 32 + ksx;

    f32x4 acc[MF][4] = {};
    const int NT = K >> 5;

    auto issue = [&](int g, short* nb, int k2) {
        if constexpr (BM == 256) {
            switch (g) {
            case 0: gld16(Ab_h + sA0 + k2, &nb[AH + d0]); break;
            case 1: gld16(Ab_h + sA1 + k2, &nb[AH + d1]); break;
            case 2: gld16(Ab_l + sA0 + k2, &nb[AL + d0]); break;
            case 3: gld16(Ab_l + sA1 + k2, &nb[AL + d1]); break;
            case 4: gld16(Bb_h + sB  + k2, &nb[BH + d0]); break;
            case 5: gld16(Bb_l + sB  + k2, &nb[BL + d0]); break;
            }
        } else {
            switch (g) {
            case 0: gld16(Ab_h + sA0 + k2, &nb[AH + d0]); break;
            case 1: gld16(Ab_l + sA0 + k2, &nb[AL + d0]); break;
            case 2: gld16(Bb_h + sB  + k2, &nb[BH + d0]); break;
            case 3: gld16(Bb_l + sB  + k2, &nb[BL + d0]); break;
            }
        }
    };

    // prologue: stage tiles 0 and 1; wait own tile-0 glds (leave tile 1 in flight)
#pragma unroll
    for (int g = 0; g < NG; ++g) issue(g, &lds[0], 0);
#pragma unroll
    for (int g = 0; g < NG; ++g) issue(g, &lds[SBUF], 32);
    if constexpr (BM == 256) asm volatile("s_waitcnt vmcnt(6)" ::: "memory");
    else                     asm volatile("s_waitcnt vmcnt(4)" ::: "memory");
    __builtin_amdgcn_s_barrier();

    int slot = 0, islot = 2;
#pragma unroll 1
    for (int t = 0; t < NT; ++t) {
        short* buf = &lds[slot * SBUF];
        short* nb  = &lds[islot * SBUF];
        const bool valid = (t + 2 < NT);
        const int k2 = (t + 2) << 5;

        // stage tile t+2 into the slot fully consumed before last barrier
        if (valid) {
#pragma unroll
            for (int g = 0; g < NG; ++g) issue(g, nb, k2);
        }

        // B frags for the whole tile; A frags staggered one phase ahead.
        s16x8 bh[4], bl[4];
#pragma unroll
        for (int n = 0; n < 4; ++n) {
            bh[n] = *(const s16x8*)&buf[BH + boff[n]];
            bl[n] = *(const s16x8*)&buf[BL + boff[n]];
        }
        s16x8 ah0 = *(const s16x8*)&buf[AH + aoff[0]];
        s16x8 al0 = *(const s16x8*)&buf[AL + aoff[0]];
#pragma unroll
        for (int p = 0; p < MF; ++p) {
            s16x8 ah1, al1;
            if (p + 1 < MF) {
                ah1 = *(const s16x8*)&buf[AH + aoff[p + 1]];
                al1 = *(const s16x8*)&buf[AL + aoff[p + 1]];
            }
            __builtin_amdgcn_s_setprio(1);
#pragma unroll
            for (int n = 0; n < 4; ++n) {
                acc[p][n] = __builtin_amdgcn_mfma_f32_16x16x32_bf16(ah0, bh[n], acc[p][n], 0, 0, 0);
                acc[p][n] = __builtin_amdgcn_mfma_f32_16x16x32_bf16(ah0, bl[n], acc[p][n], 0, 0, 0);
                acc[p][n] = __builtin_amdgcn_mfma_f32_16x16x32_bf16(al0, bh[n], acc[p][n], 0, 0, 0);
            }
            __builtin_amdgcn_s_setprio(0);
            if (p + 1 < MF) { ah0 = ah1; al0 = al1; }
        }

        // one counted wait + one barrier per K-tile
        if (valid) {
            if constexpr (BM == 256) asm volatile("s_waitcnt vmcnt(6)" ::: "memory");
            else                     asm volatile("s_waitcnt vmcnt(4)" ::: "memory");
        } else {
            asm volatile("s_waitcnt vmcnt(0)" ::: "memory");
        }
        __builtin_amdgcn_s_barrier();
        slot  = (slot  == 2) ? 0 : slot + 1;
        islot = (islot == 2) ? 0 : islot + 1;
    }

    // epilogue (C/D map: col = lane&15, row = (lane>>4)*4 + j)
    const int row0 = bm * BM + wr * (BM / 4);
    const int col0 = bn * BN + wc * 64;
#pragma unroll
    for (int n = 0; n < 4; ++n) {
        const int col = col0 + n * 16 + l15;
        float bv = 0.0f;
        if constexpr (ACT) bv = bias[col];
#pragma unroll
        for (int m = 0; m < MF; ++m) {
#pragma unroll
            for (int j = 0; j < 4; ++j) {
                const int row = row0 + m * 16 + ks * 4 + j;
                float v = acc[m][n][j];
                if constexpr (ACT) {
                    v = tanhf(v + bv);
                    const short h = f2bf(v);
                    Chi[(size_t)row * N + col] = h;
                    Clo[(size_t)row * N + col] = f2bf(v - bf2f(h));
                } else {
                    Cf[(size_t)row * N + col] = v;
                }
            }
        }
    }
}

// f32 src -> hi/lo bf16 split (grid-stride, float4). Elements >= n_src -> 0.
__global__ __launch_bounds__(256)
void pack_split(const float* __restrict__ src, long n_src,
                short* __restrict__ hi, short* __restrict__ lo, long n_total)
{
    const long stride = (long)gridDim.x * 1024;
    for (long i4 = ((long)blockIdx.x * 256 + threadIdx.x) * 4; i4 < n_total; i4 += stride) {
        float a[4] = {0.f, 0.f, 0.f, 0.f};
        if (i4 < n_src) {
            const float4 v = *(const float4*)&src[i4];
            a[0] = v.x; a[1] = v.y; a[2] = v.z; a[3] = v.w;
        }
        s16x4 h, l;
#pragma unroll
        for (int j = 0; j < 4; ++j) {
            h[j] = f2bf(a[j]);
            l[j] = f2bf(a[j] - bf2f(h[j]));
        }
        *(s16x4*)&hi[i4] = h;
        *(s16x4*)&lo[i4] = l;
    }
}

// W[K][N] f32 -> Thi/Tlo[N][K] bf16. Block (32,8), 32x32 LDS tile.
__global__ __launch_bounds__(256)
void transpose_split(const float* __restrict__ W,
                     short* __restrict__ Thi, short* __restrict__ Tlo,
                     int K, int N)
{
    __shared__ float t[32][33];
    const int tx = threadIdx.x, ty = threadIdx.y;
    const int n0 = blockIdx.x * 32, k0 = blockIdx.y * 32;
#pragma unroll
    for (int i = 0; i < 4; ++i)
        t[ty * 4 + i][tx] = W[(size_t)(k0 + ty * 4 + i) * N + n0 + tx];
    __syncthreads();
#pragma unroll
    for (int i = 0; i < 4; ++i) {
        const int n = n0 + ty * 4 + i;
        const float v = t[tx][ty * 4 + i];
        const short h = f2bf(v);
        Thi[(size_t)n * K + k0 + tx] = h;
        Tlo[(size_t)n * K + k0 + tx] = f2bf(v - bf2f(h));
    }
}

// Vsq[h][d] = sum_r V[h][r][d]^2
__global__ __launch_bounds__(256)
void fm_vsq(const float* __restrict__ V, float* __restrict__ Vsq)
{
    const int h = blockIdx.x;
    for (int d = threadIdx.x; d < HIDDEN_N; d += 256) {
        float s = 0.0f;
#pragma unroll
        for (int r = 0; r < RANK_N; ++r) {
            const float v = V[((size_t)h * RANK_N + r) * HIDDEN_N + d];
            s = fmaf(v, v, s);
        }
        Vsq[(size_t)h * HIDDEN_N + d] = s;
    }
}

// D[m][64] = (h3[m].^2) @ Vsq^T ; A from hi/lo bf16, 32x64 tile, BK=16
__global__ __launch_bounds__(256)
void gemm_diag(const short* __restrict__ Ahi, const short* __restrict__ Alo,
               const float* __restrict__ Vsq, float* __restrict__ D, int K)
{
    __shared__ float As[16][36];
    __shared__ float Bs[16][68];
    const int tid = threadIdx.x;
    const int tr = tid >> 4, tc = tid & 15;
    const int bm = blockIdx.x;
    float acc[2][4] = {};
    for (int k0 = 0; k0 < K; k0 += 16) {
        if (tid < 128) {
            const int row = tid >> 2, cv = (tid & 3) * 4;
            const size_t off = (size_t)(bm * 32 + row) * K + k0 + cv;
            const s16x4 h = *(const s16x4*)&Ahi[off];
            const s16x4 l = *(const s16x4*)&Alo[off];
#pragma unroll
            for (int j = 0; j < 4; ++j) {
                const float f = bf2f(h[j]) + bf2f(l[j]);
                As[cv + j][row] = f * f;
            }
        }
        {
            const int row = tid >> 2, cv = (tid & 3) * 4;
            const float4 v = *(const float4*)&Vsq[(size_t)row * K + k0 + cv];
            Bs[cv + 0][row] = v.x; Bs[cv + 1][row] = v.y;
            Bs[cv + 2][row] = v.z; Bs[cv + 3][row] = v.w;
        }
        __syncthreads();
#pragma unroll
        for (int kk = 0; kk < 16; ++kk) {
            const float a0 = As[kk][tr * 2], a1 = As[kk][tr * 2 + 1];
            const float4 b = *(const float4*)&Bs[kk][tc * 4];
            acc[0][0] = fmaf(a0, b.x, acc[0][0]); acc[0][1] = fmaf(a0, b.y, acc[0][1]);
            acc[0][2] = fmaf(a0, b.z, acc[0][2]); acc[0][3] = fmaf(a0, b.w, acc[0][3]);
            acc[1][0] = fmaf(a1, b.x, acc[1][0]); acc[1][1] = fmaf(a1, b.y, acc[1][1]);
            acc[1][2] = fmaf(a1, b.z, acc[1][2]); acc[1][3] = fmaf(a1, b.w, acc[1][3]);
        }
        __syncthreads();
    }
#pragma unroll
    for (int i = 0; i < 2; ++i)
#pragma unroll
        for (int j = 0; j < 4; ++j)
            D[(size_t)(bm * 32 + tr * 2 + i) * 64 + tc * 4 + j] = acc[i][j];
}

// out[h, boff+b] = w0[h] + P[b,h] + 0.5*(sum_r P[b,64+16h+r]^2 - D[b,h])
// one wave per batch row; fully coalesced P reads.
__global__ __launch_bounds__(256)
void fm_combine(const float* __restrict__ P, const float* __restrict__ D,
                const float* __restrict__ w0, float* __restrict__ out, int boff)
{
    const int wave = threadIdx.x >> 6, lane = threadIdx.x & 63;
    const int b = blockIdx.x * 4 + wave;
    const float* Pb = P + (size_t)b * PN;
    const float* Db = D + (size_t)b * 64;
    const int hl = lane & 15, part = lane >> 4;
#pragma unroll
    for (int hb = 0; hb < 4; ++hb) {
        const float4 v = *(const float4*)&Pb[64 + hb * 256 + hl * 16 + part * 4];
        float q = fmaf(v.x, v.x, fmaf(v.y, v.y, fmaf(v.z, v.z, v.w * v.w)));
        q += __shfl_xor(q, 16);
        q += __shfl_xor(q, 32);
        if (part == 0) {
            const int h = hb * 16 + hl;
            out[(size_t)h * BATCH_N + boff + b] = w0[h] + Pb[h] + 0.5f * (q - Db[h]);
        }
    }
}

extern "C" void kernel_launch(void* const* d_in, const int* in_sizes, int n_in,
                              void* d_out, int out_size, void* d_ws, size_t ws_size,
                              hipStream_t stream)
{
    const float* x   = (const float*)d_in[0];
    const float* W1  = (const float*)d_in[1];
    const float* b1  = (const float*)d_in[2];
    const float* W2  = (const float*)d_in[3];
    const float* b2  = (const float*)d_in[4];
    const float* W3  = (const float*)d_in[5];
    const float* b3  = (const float*)d_in[6];
    const float* fw0 = (const float*)d_in[7];
    const float* fw  = (const float*)d_in[8];
    const float* fV  = (const float*)d_in[9];
    float* out = (float*)d_out;

    // single-pass if workspace allows (needs ~182 MB), else 2 chunks
    const int CH = (ws_size >= (188ull << 20)) ? 8192 : 4096;
    const int nchunk = BATCH_N / CH;

    char* ws = (char*)d_ws;
    size_t o = 0;
    auto alloc = [&](size_t bytes) { void* p = ws + o; o += (bytes + 255) & ~(size_t)255; return p; };

    short* W1h = (short*)alloc((size_t)HIDDEN_N * IN_SIZE_N * 2);
    short* W1l = (short*)alloc((size_t)HIDDEN_N * IN_SIZE_N * 2);
    short* W2h = (short*)alloc((size_t)HIDDEN_N * HIDDEN_N * 2);
    short* W2l = (short*)alloc((size_t)HIDDEN_N * HIDDEN_N * 2);
    short* W3h = (short*)alloc((size_t)HIDDEN_N * HIDDEN_N * 2);
    short* W3l = (short*)alloc((size_t)HIDDEN_N * HIDDEN_N * 2);
    short* PBh = (short*)alloc((size_t)PN * HIDDEN_N * 2);
    short* PBl = (short*)alloc((size_t)PN * HIDDEN_N * 2);
    float* Vsq = (float*)alloc((size_t)HEADS_N * HIDDEN_N * 4);
    short* hAh = (short*)alloc((size_t)CH * HIDDEN_N * 2);
    short* hAl = (short*)alloc((size_t)CH * HIDDEN_N * 2);
    char*  hBb = (char*) alloc((size_t)CH * HIDDEN_N * 4);   // hBh+hBl contiguous
    short* hBh = (short*)hBb;
    short* hBl = hBh + (size_t)CH * HIDDEN_N;
    short* xh  = (short*)hBb;                      // alias (dead when h2/P live)
    short* xl  = xh + (size_t)CH * IN_SIZE_N;
    float* P   = (float*)hBb;                      // [CH][PN] f32, alias of hB
    float* Dg  = (float*)(hBb + (size_t)CH * PN * 4);

    const dim3 blk(256, 1, 1);
    const dim3 blk512(512, 1, 1);

    // one-time packs
    transpose_split<<<dim3(HIDDEN_N / 32, IN_SIZE_N / 32), dim3(32, 8), 0, stream>>>(W1, W1h, W1l, IN_SIZE_N, HIDDEN_N);
    transpose_split<<<dim3(HIDDEN_N / 32, HIDDEN_N / 32), dim3(32, 8), 0, stream>>>(W2, W2h, W2l, HIDDEN_N, HIDDEN_N);
    transpose_split<<<dim3(HIDDEN_N / 32, HIDDEN_N / 32), dim3(32, 8), 0, stream>>>(W3, W3h, W3l, HIDDEN_N, HIDDEN_N);
    pack_split<<<dim3(128), blk, 0, stream>>>(fw, (long)HEADS_N * HIDDEN_N, PBh, PBl, (long)HEADS_N * HIDDEN_N);
    pack_split<<<dim3(1024), blk, 0, stream>>>(fV, (long)HEADS_N * RANK_N * HIDDEN_N,
                                               PBh + (size_t)HEADS_N * HIDDEN_N,
                                               PBl + (size_t)HEADS_N * HIDDEN_N,
                                               (long)(PN - HEADS_N) * HIDDEN_N);
    fm_vsq<<<dim3(HEADS_N), blk, 0, stream>>>(fV, Vsq);

    for (int c = 0; c < nchunk; ++c) {
        pack_split<<<dim3(1024), blk, 0, stream>>>(x + (size_t)c * CH * IN_SIZE_N,
                                                   (long)CH * IN_SIZE_N, xh, xl, (long)CH * IN_SIZE_N);
        // h1 = tanh(x W1 + b1)
        gemm8<256, true><<<dim3((HIDDEN_N / 128) * (CH / 256)), blk512, 0, stream>>>(
            xh, xl, W1h, W1l, b1, hAh, hAl, nullptr, HIDDEN_N / 128, HIDDEN_N, IN_SIZE_N);
        // h2
        gemm8<256, true><<<dim3((HIDDEN_N / 128) * (CH / 256)), blk512, 0, stream>>>(
            hAh, hAl, W2h, W2l, b2, hBh, hBl, nullptr, HIDDEN_N / 128, HIDDEN_N, HIDDEN_N);
        // h3 (overwrites h1)
        gemm8<256, true><<<dim3((HIDDEN_N / 128) * (CH / 256)), blk512, 0, stream>>>(
            hBh, hBl, W3h, W3l, b3, hAh, hAl, nullptr, HIDDEN_N / 128, HIDDEN_N, HIDDEN_N);
        // P = h3 @ [fm_w; fm_V]^T   (f32 out, overwrites h2 region)
        gemm8<128, false><<<dim3((PN / 128) * (CH / 128)), blk512, 0, stream>>>(
            hAh, hAl, PBh, PBl, nullptr, nullptr, nullptr, P, PN / 128, PN, HIDDEN_N);
        // D = h3^2 @ Vsq^T
        gemm_diag<<<dim3(CH / 32), blk, 0, stream>>>(hAh, hAl, Vsq, Dg, HIDDEN_N);
        fm_combine<<<dim3(CH / 4), blk, 0, stream>>>(P, Dg, fw0, out, c * CH);
    }
}

// Round 6
// 754.734 us; speedup vs baseline: 1.2537x; 1.0167x over previous
//
#include <hip/hip_runtime.h>
#include <math.h>

#define BATCH_N   8192
#define IN_SIZE_N  512
#define HIDDEN_N  2048
#define HEADS_N     64
#define RANK_N      16
#define PN        1152   // padded FM-head GEMM width: 64 lin + 1024 vx + 64 pad

typedef short s16x4 __attribute__((ext_vector_type(4)));
typedef short s16x8 __attribute__((ext_vector_type(8)));
typedef float f32x4 __attribute__((ext_vector_type(4)));
typedef float f32x16 __attribute__((ext_vector_type(16)));
typedef unsigned int u32;

__device__ __forceinline__ short f2bf(float f) {
    __bf16 b = (__bf16)f; short r; __builtin_memcpy(&r, &b, 2); return r;
}
__device__ __forceinline__ float bf2f(short s) {
    __bf16 b; __builtin_memcpy(&b, &s, 2); return (float)b;
}
__device__ __forceinline__ void gld16(const void* g, void* l) {
    __builtin_amdgcn_global_load_lds(
        (const __attribute__((address_space(1))) u32*)g,
        (__attribute__((address_space(3))) u32*)l, 16, 0, 0);
}

// ---------------------------------------------------------------------------
// Split-bf16 MFMA GEMM on 32x32x16 fragments.
// C = act(A @ Bt^T + bias); A=[M][K] hi/lo bf16, Bt=[N][K] hi/lo bf16.
// Tile 256 x BN, BK=32, 1024 threads (16 waves), per-wave 64x64 (BN=256,
// 4Mx4N) or 32x64 (BN=128, 8Mx2N). TWO LDS slots; body t stages t+1 via
// global_load_lds, computes t, then vmcnt(0)+one barrier (drain is free:
// tile compute ~3.4k cyc >> HBM latency).
// LDS swizzle for 32-row fragment reads: chunk (row, j) stored at index
// row*4 + (j ^ ((row>>1)&3)). For a 32x32 frag read (lane l: row=l&31,
// chunk j = 2*k2 + (l>>5)), the 16B-granule index mod 8 is
// 4*(row&1) + (j ^ ((row>>1)&3)) -> exactly 8 lanes per granule group
// over the 64-lane wave = minimum LDS occupancy (conflict-free).
// Staged via pre-swizzled GLOBAL source, linear LDS dest (G21).
// ---------------------------------------------------------------------------
template<int BN, bool ACT>
__global__ __launch_bounds__(1024)
void gemm32(const short* __restrict__ Ahi, const short* __restrict__ Alo,
            const short* __restrict__ Bhi, const short* __restrict__ Blo,
            const float* __restrict__ bias,
            short* __restrict__ Chi, short* __restrict__ Clo,
            float* __restrict__ Cf,
            int GX, int N, int K)
{
    constexpr int BM = 256;
    constexpr int NWC = BN / 64;              // waves along N (4 or 2)
    constexpr int WM  = (BN == 256) ? 2 : 1;  // 32-row m-frags per wave
    constexpr int AH = 0;
    constexpr int AL = BM * 32;
    constexpr int BH = 2 * BM * 32;
    constexpr int BL = 2 * BM * 32 + BN * 32;
    constexpr int SBUF = 2 * BM * 32 + 2 * BN * 32;
    __shared__ __align__(16) short lds[2 * SBUF];

    const int tid = threadIdx.x;
    const int lane = tid & 63, wv = tid >> 6;
    const int wr = wv / NWC, wc = wv % NWC;
    const int la = lane & 31, jh = lane >> 5;

    // XCD-aware swizzle (gridDim.x % 8 == 0 for all our launches)
    const int flat = blockIdx.x;
    const int wg = (flat & 7) * (gridDim.x >> 3) + (flat >> 3);
    const int bn = wg % GX, bm = wg / GX;

    const short* Ab_h = Ahi + (size_t)bm * BM * K;
    const short* Ab_l = Alo + (size_t)bm * BM * K;
    const short* Bb_h = Bhi + (size_t)bn * BN * K;
    const short* Bb_l = Blo + (size_t)bn * BN * K;

    // staging: LDS chunk c = tid (linear) <- global (row=c>>2, seg=(c&3)^((c>>3)&3))
    const size_t sA = (size_t)(tid >> 2) * K + (size_t)(((tid & 3) ^ ((tid >> 3) & 3)) * 8);
    const int d0 = (tid & ~63) * 8;           // wave-uniform LDS el offset

    // frag read base addrs (elements); k2 toggles by XOR 16 (chunk bit1)
    const int sw = (la >> 1) & 3;
    int aoffb[WM], boffb[2];
#pragma unroll
    for (int m = 0; m < WM; ++m)
        aoffb[m] = (wr * (WM * 32) + m * 32 + la) * 32 + ((jh ^ sw) * 8);
#pragma unroll
    for (int n = 0; n < 2; ++n)
        boffb[n] = (wc * 64 + n * 32 + la) * 32 + ((jh ^ sw) * 8);

    f32x16 acc[WM][2] = {};
    const int NT = K >> 5;

    auto stage = [&](short* nb, int kt) {
        gld16(Ab_h + sA + kt, &nb[AH + d0]);
        gld16(Ab_l + sA + kt, &nb[AL + d0]);
        if constexpr (BN == 256) {
            gld16(Bb_h + sA + kt, &nb[BH + d0]);
            gld16(Bb_l + sA + kt, &nb[BL + d0]);
        } else {
            if (tid < 512) {   // wave-uniform: waves 0-7 stage B (128 rows)
                gld16(Bb_h + sA + kt, &nb[BH + d0]);
                gld16(Bb_l + sA + kt, &nb[BL + d0]);
            }
        }
    };

    stage(&lds[0], 0);
    asm volatile("s_waitcnt vmcnt(0)" ::: "memory");
    __builtin_amdgcn_s_barrier();

#pragma unroll 1
    for (int t = 0; t < NT; ++t) {
        short* buf = &lds[(t & 1) * SBUF];
        if (t + 1 < NT) stage(&lds[((t + 1) & 1) * SBUF], (t + 1) << 5);

        // B frags for the whole tile (8 reads); A JIT-staggered per phase
        s16x8 bh[2][2], bl[2][2];   // [k2][n]
#pragma unroll
        for (int k2 = 0; k2 < 2; ++k2)
#pragma unroll
            for (int n = 0; n < 2; ++n) {
                bh[k2][n] = *(const s16x8*)&buf[BH + (boffb[n] ^ (k2 * 16))];
                bl[k2][n] = *(const s16x8*)&buf[BL + (boffb[n] ^ (k2 * 16))];
            }
        s16x8 ah = *(const s16x8*)&buf[AH + aoffb[0]];
        s16x8 al = *(const s16x8*)&buf[AL + aoffb[0]];
#pragma unroll
        for (int ph = 0; ph < 2 * WM; ++ph) {
            const int k2 = ph / WM, m = ph % WM;
            s16x8 ahn, aln;
            if (ph + 1 < 2 * WM) {
                const int k2n = (ph + 1) / WM, mn = (ph + 1) % WM;
                ahn = *(const s16x8*)&buf[AH + (aoffb[mn] ^ (k2n * 16))];
                aln = *(const s16x8*)&buf[AL + (aoffb[mn] ^ (k2n * 16))];
            }
            __builtin_amdgcn_s_setprio(1);
#pragma unroll
            for (int n = 0; n < 2; ++n) {
                acc[m][n] = __builtin_amdgcn_mfma_f32_32x32x16_bf16(ah, bh[k2][n], acc[m][n], 0, 0, 0);
                acc[m][n] = __builtin_amdgcn_mfma_f32_32x32x16_bf16(ah, bl[k2][n], acc[m][n], 0, 0, 0);
                acc[m][n] = __builtin_amdgcn_mfma_f32_32x32x16_bf16(al, bh[k2][n], acc[m][n], 0, 0, 0);
            }
            __builtin_amdgcn_s_setprio(0);
            if (ph + 1 < 2 * WM) { ah = ahn; al = aln; }
        }

        asm volatile("s_waitcnt vmcnt(0)" ::: "memory");
        __builtin_amdgcn_s_barrier();
    }

    // epilogue; 32x32 C/D map: col = lane&31, row = (reg&3) + 8*(reg>>2) + 4*(lane>>5)
    const int row0 = bm * BM + wr * (WM * 32);
    const int col0 = bn * BN + wc * 64;
#pragma unroll
    for (int m = 0; m < WM; ++m) {
#pragma unroll
        for (int n = 0; n < 2; ++n) {
            const int col = col0 + n * 32 + la;
            float bv = 0.0f;
            if constexpr (ACT) bv = bias[col];
#pragma unroll
            for (int rg = 0; rg < 4; ++rg) {
#pragma unroll
                for (int rj = 0; rj < 4; ++rj) {
                    const int row = row0 + m * 32 + jh * 4 + rg * 8 + rj;
                    float v = acc[m][n][rg * 4 + rj];
                    if constexpr (ACT) {
                        v = tanhf(v + bv);
                        const short h = f2bf(v);
                        Chi[(size_t)row * N + col] = h;
                        Clo[(size_t)row * N + col] = f2bf(v - bf2f(h));
                    } else {
                        Cf[(size_t)row * N + col] = v;
                    }
                }
            }
        }
    }
}

// f32 src -> hi/lo bf16 split (grid-stride, float4). Elements >= n_src -> 0.
__global__ __launch_bounds__(256)
void pack_split(const float* __restrict__ src, long n_src,
                short* __restrict__ hi, short* __restrict__ lo, long n_total)
{
    const long stride = (long)gridDim.x * 1024;
    for (long i4 = ((long)blockIdx.x * 256 + threadIdx.x) * 4; i4 < n_total; i4 += stride) {
        float a[4] = {0.f, 0.f, 0.f, 0.f};
        if (i4 < n_src) {
            const float4 v = *(const float4*)&src[i4];
            a[0] = v.x; a[1] = v.y; a[2] = v.z; a[3] = v.w;
        }
        s16x4 h, l;
#pragma unroll
        for (int j = 0; j < 4; ++j) {
            h[j] = f2bf(a[j]);
            l[j] = f2bf(a[j] - bf2f(h[j]));
        }
        *(s16x4*)&hi[i4] = h;
        *(s16x4*)&lo[i4] = l;
    }
}

// W[K][N] f32 -> Thi/Tlo[N][K] bf16. Block (32,8), 32x32 LDS tile.
__global__ __launch_bounds__(256)
void transpose_split(const float* __restrict__ W,
                     short* __restrict__ Thi, short* __restrict__ Tlo,
                     int K, int N)
{
    __shared__ float t[32][33];
    const int tx = threadIdx.x, ty = threadIdx.y;
    const int n0 = blockIdx.x * 32, k0 = blockIdx.y * 32;
#pragma unroll
    for (int i = 0; i < 4; ++i)
        t[ty * 4 + i][tx] = W[(size_t)(k0 + ty * 4 + i) * N + n0 + tx];
    __syncthreads();
#pragma unroll
    for (int i = 0; i < 4; ++i) {
        const int n = n0 + ty * 4 + i;
        const float v = t[tx][ty * 4 + i];
        const short h = f2bf(v);
        Thi[(size_t)n * K + k0 + tx] = h;
        Tlo[(size_t)n * K + k0 + tx] = f2bf(v - bf2f(h));
    }
}

// Vsq[h][d] = sum_r V[h][r][d]^2
__global__ __launch_bounds__(256)
void fm_vsq(const float* __restrict__ V, float* __restrict__ Vsq)
{
    const int h = blockIdx.x;
    for (int d = threadIdx.x; d < HIDDEN_N; d += 256) {
        float s = 0.0f;
#pragma unroll
        for (int r = 0; r < RANK_N; ++r) {
            const float v = V[((size_t)h * RANK_N + r) * HIDDEN_N + d];
            s = fmaf(v, v, s);
        }
        Vsq[(size_t)h * HIDDEN_N + d] = s;
    }
}

// D[m][64] = (h3[m].^2) @ Vsq^T ; A from hi/lo bf16, 32x64 tile, BK=16
__global__ __launch_bounds__(256)
void gemm_diag(const short* __restrict__ Ahi, const short* __restrict__ Alo,
               const float* __restrict__ Vsq, float* __restrict__ D, int K)
{
    __shared__ float As[16][36];
    __shared__ float Bs[16][68];
    const int tid = threadIdx.x;
    const int tr = tid >> 4, tc = tid & 15;
    const int bm = blockIdx.x;
    float acc[2][4] = {};
    for (int k0 = 0; k0 < K; k0 += 16) {
        if (tid < 128) {
            const int row = tid >> 2, cv = (tid & 3) * 4;
            const size_t off = (size_t)(bm * 32 + row) * K + k0 + cv;
            const s16x4 h = *(const s16x4*)&Ahi[off];
            const s16x4 l = *(const s16x4*)&Alo[off];
#pragma unroll
            for (int j = 0; j < 4; ++j) {
                const float f = bf2f(h[j]) + bf2f(l[j]);
                As[cv + j][row] = f * f;
            }
        }
        {
            const int row = tid >> 2, cv = (tid & 3) * 4;
            const float4 v = *(const float4*)&Vsq[(size_t)row * K + k0 + cv];
            Bs[cv + 0][row] = v.x; Bs[cv + 1][row] = v.y;
            Bs[cv + 2][row] = v.z; Bs[cv + 3][row] = v.w;
        }
        __syncthreads();
#pragma unroll
        for (int kk = 0; kk < 16; ++kk) {
            const float a0 = As[kk][tr * 2], a1 = As[kk][tr * 2 + 1];
            const float4 b = *(const float4*)&Bs[kk][tc * 4];
            acc[0][0] = fmaf(a0, b.x, acc[0][0]); acc[0][1] = fmaf(a0, b.y, acc[0][1]);
            acc[0][2] = fmaf(a0, b.z, acc[0][2]); acc[0][3] = fmaf(a0, b.w, acc[0][3]);
            acc[1][0] = fmaf(a1, b.x, acc[1][0]); acc[1][1] = fmaf(a1, b.y, acc[1][1]);
            acc[1][2] = fmaf(a1, b.z, acc[1][2]); acc[1][3] = fmaf(a1, b.w, acc[1][3]);
        }
        __syncthreads();
    }
#pragma unroll
    for (int i = 0; i < 2; ++i)
#pragma unroll
        for (int j = 0; j < 4; ++j)
            D[(size_t)(bm * 32 + tr * 2 + i) * 64 + tc * 4 + j] = acc[i][j];
}

// out[h, boff+b] = w0[h] + P[b,h] + 0.5*(sum_r P[b,64+16h+r]^2 - D[b,h])
// one wave per batch row; fully coalesced P reads.
__global__ __launch_bounds__(256)
void fm_combine(const float* __restrict__ P, const float* __restrict__ D,
                const float* __restrict__ w0, float* __restrict__ out, int boff)
{
    const int wave = threadIdx.x >> 6, lane = threadIdx.x & 63;
    const int b = blockIdx.x * 4 + wave;
    const float* Pb = P + (size_t)b * PN;
    const float* Db = D + (size_t)b * 64;
    const int hl = lane & 15, part = lane >> 4;
#pragma unroll
    for (int hb = 0; hb < 4; ++hb) {
        const float4 v = *(const float4*)&Pb[64 + hb * 256 + hl * 16 + part * 4];
        float q = fmaf(v.x, v.x, fmaf(v.y, v.y, fmaf(v.z, v.z, v.w * v.w)));
        q += __shfl_xor(q, 16);
        q += __shfl_xor(q, 32);
        if (part == 0) {
            const int h = hb * 16 + hl;
            out[(size_t)h * BATCH_N + boff + b] = w0[h] + Pb[h] + 0.5f * (q - Db[h]);
        }
    }
}

extern "C" void kernel_launch(void* const* d_in, const int* in_sizes, int n_in,
                              void* d_out, int out_size, void* d_ws, size_t ws_size,
                              hipStream_t stream)
{
    const float* x   = (const float*)d_in[0];
    const float* W1  = (const float*)d_in[1];
    const float* b1  = (const float*)d_in[2];
    const float* W2  = (const float*)d_in[3];
    const float* b2  = (const float*)d_in[4];
    const float* W3  = (const float*)d_in[5];
    const float* b3  = (const float*)d_in[6];
    const float* fw0 = (const float*)d_in[7];
    const float* fw  = (const float*)d_in[8];
    const float* fV  = (const float*)d_in[9];
    float* out = (float*)d_out;

    // single-pass if workspace allows (needs ~175 MB), else 2 chunks
    const int CH = (ws_size >= (188ull << 20)) ? 8192 : 4096;
    const int nchunk = BATCH_N / CH;

    char* ws = (char*)d_ws;
    size_t o = 0;
    auto alloc = [&](size_t bytes) { void* p = ws + o; o += (bytes + 255) & ~(size_t)255; return p; };

    short* W1h = (short*)alloc((size_t)HIDDEN_N * IN_SIZE_N * 2);
    short* W1l = (short*)alloc((size_t)HIDDEN_N * IN_SIZE_N * 2);
    short* W2h = (short*)alloc((size_t)HIDDEN_N * HIDDEN_N * 2);
    short* W2l = (short*)alloc((size_t)HIDDEN_N * HIDDEN_N * 2);
    short* W3h = (short*)alloc((size_t)HIDDEN_N * HIDDEN_N * 2);
    short* W3l = (short*)alloc((size_t)HIDDEN_N * HIDDEN_N * 2);
    short* PBh = (short*)alloc((size_t)PN * HIDDEN_N * 2);
    short* PBl = (short*)alloc((size_t)PN * HIDDEN_N * 2);
    float* Vsq = (float*)alloc((size_t)HEADS_N * HIDDEN_N * 4);
    short* hAh = (short*)alloc((size_t)CH * HIDDEN_N * 2);
    short* hAl = (short*)alloc((size_t)CH * HIDDEN_N * 2);
    char*  hBb = (char*) alloc((size_t)CH * HIDDEN_N * 4);   // hBh+hBl contiguous
    short* hBh = (short*)hBb;
    short* hBl = hBh + (size_t)CH * HIDDEN_N;
    short* xh  = (short*)hBb;                      // alias (dead when h2/P live)
    short* xl  = xh + (size_t)CH * IN_SIZE_N;
    float* P   = (float*)hBb;                      // [CH][PN] f32, alias of hB
    float* Dg  = (float*)(hBb + (size_t)CH * PN * 4);

    const dim3 blk(256, 1, 1);
    const dim3 blk1k(1024, 1, 1);

    // one-time packs
    transpose_split<<<dim3(HIDDEN_N / 32, IN_SIZE_N / 32), dim3(32, 8), 0, stream>>>(W1, W1h, W1l, IN_SIZE_N, HIDDEN_N);
    transpose_split<<<dim3(HIDDEN_N / 32, HIDDEN_N / 32), dim3(32, 8), 0, stream>>>(W2, W2h, W2l, HIDDEN_N, HIDDEN_N);
    transpose_split<<<dim3(HIDDEN_N / 32, HIDDEN_N / 32), dim3(32, 8), 0, stream>>>(W3, W3h, W3l, HIDDEN_N, HIDDEN_N);
    pack_split<<<dim3(128), blk, 0, stream>>>(fw, (long)HEADS_N * HIDDEN_N, PBh, PBl, (long)HEADS_N * HIDDEN_N);
    pack_split<<<dim3(1024), blk, 0, stream>>>(fV, (long)HEADS_N * RANK_N * HIDDEN_N,
                                               PBh + (size_t)HEADS_N * HIDDEN_N,
                                               PBl + (size_t)HEADS_N * HIDDEN_N,
                                               (long)(PN - HEADS_N) * HIDDEN_N);
    fm_vsq<<<dim3(HEADS_N), blk, 0, stream>>>(fV, Vsq);

    for (int c = 0; c < nchunk; ++c) {
        pack_split<<<dim3(1024), blk, 0, stream>>>(x + (size_t)c * CH * IN_SIZE_N,
                                                   (long)CH * IN_SIZE_N, xh, xl, (long)CH * IN_SIZE_N);
        // h1 = tanh(x W1 + b1)
        gemm32<256, true><<<dim3((HIDDEN_N / 256) * (CH / 256)), blk1k, 0, stream>>>(
            xh, xl, W1h, W1l, b1, hAh, hAl, nullptr, HIDDEN_N / 256, HIDDEN_N, IN_SIZE_N);
        // h2
        gemm32<256, true><<<dim3((HIDDEN_N / 256) * (CH / 256)), blk1k, 0, stream>>>(
            hAh, hAl, W2h, W2l, b2, hBh, hBl, nullptr, HIDDEN_N / 256, HIDDEN_N, HIDDEN_N);
        // h3 (overwrites h1)
        gemm32<256, true><<<dim3((HIDDEN_N / 256) * (CH / 256)), blk1k, 0, stream>>>(
            hBh, hBl, W3h, W3l, b3, hAh, hAl, nullptr, HIDDEN_N / 256, HIDDEN_N, HIDDEN_N);
        // P = h3 @ [fm_w; fm_V]^T   (f32 out, overwrites h2 region)
        gemm32<128, false><<<dim3((PN / 128) * (CH / 256)), blk1k, 0, stream>>>(
            hAh, hAl, PBh, PBl, nullptr, nullptr, nullptr, P, PN / 128, PN, HIDDEN_N);
        // D = h3^2 @ Vsq^T
        gemm_diag<<<dim3(CH / 32), blk, 0, stream>>>(hAh, hAl, Vsq, Dg, HIDDEN_N);
        fm_combine<<<dim3(CH / 4), blk, 0, stream>>>(P, Dg, fw0, out, c * CH);
    }
}